// Round 1
// baseline (5598.897 us; speedup 1.0000x reference)
//
#include <hip/hip_runtime.h>

// ---------------- problem constants ----------------
#define Bn 32
#define Tn 64
#define Pn 196      // 14*14 encoder pixels
#define ENCD 2048
#define DECD 512
#define ATTD 512
#define FLATD 3072
#define EMBD 256
#define IMGD 512
#define PADW 24
#define XDIM 2304   // ENC_D + EMB

// ---------------- output offsets (floats) ----------------
#define O_PRED   0        // [32][64][2]
#define O_STOP   4096     // [32][64]
#define O_SEQOFF 6144     // [32][64][2]
#define O_LEN    10240    // [32]
#define O_ALPHA  10272    // [32][64][196]
#define O_SORT   411680   // [32]

// ---------------- workspace offsets (floats/ints) ----------------
#define WS_SORT   0        // int[32]
#define WS_LEN    32       // int[32]
#define WS_H      64       // [32][512]
#define WS_C      16448    // [32][512]
#define WS_SCORES 32832    // [32][256]
#define WS_XA     41024    // [32][2304]
#define WS_PA     114752   // [2][32][4608]  (att2 rows 0..511 | gateRaw 512..2559 | hhRaw 2560..4607)
#define WS_PC     409664   // [8][32][2048]
#define WS_ENCM   933952   // [32][2048]
#define WS_EMB    999488   // [32][64][256]
#define WS_WPET   1523776  // [3072][256]
#define WS_ATT1   2310208  // [6272][512]   (m = b*196+p, sorted order)

// ============ prep: stable descending sort of caption lengths ============
__global__ void k_prep(const int* __restrict__ caplen, int* __restrict__ ws_sort,
                       int* __restrict__ ws_len, float* __restrict__ out){
  __shared__ int len[32];
  int i = threadIdx.x;
  if (i < 32) len[i] = caplen[i];
  __syncthreads();
  if (i < 32){
    int li = len[i], r = 0;
    for (int j = 0; j < 32; j++){
      int lj = len[j];
      r += (lj > li) || (lj == li && j < i);
    }
    ws_sort[r] = i;
    ws_len[r]  = li;
    out[O_LEN + r]  = (float)li;
    out[O_SORT + r] = (float)i;
  }
}

// ============ gather sorted sequence_offset -> output ============
__global__ void k_seqoff(const float* __restrict__ seqoff, const int* __restrict__ ws_sort,
                         float* __restrict__ out){
  int idx = blockIdx.x*256 + threadIdx.x;    // < 4096
  int b = idx >> 7, r = idx & 127;
  out[O_SEQOFF + idx] = seqoff[ws_sort[b]*128 + r];
}

// ============ transpose W_pe (256,3072) -> (3072,256) ============
__global__ void k_wpet(const float* __restrict__ W_pe, float* __restrict__ wpet){
  int idx = blockIdx.x*256 + threadIdx.x;    // < 786432
  int e = idx / 3072, f = idx - e*3072;
  wpet[f*256 + e] = W_pe[idx];
}

// ============ patch extraction + embedding GEMM ============
// grid 256 = 32 b * 8 e-chunks(32 e each); per block: all 64 t, K=3072 in 16 passes of 192
__global__ __launch_bounds__(256) void k_embed(const float* __restrict__ imgs,
    const int* __restrict__ seq, const int* __restrict__ ws_sort,
    const float* __restrict__ wpet, const float* __restrict__ b_pe, float* __restrict__ emb){
  int b = blockIdx.x >> 3, ec = blockIdx.x & 7;
  int e0 = ec * 32;
  int sb = ws_sort[b];
  const float* img = imgs + (size_t)sb*(3*512*512);
  __shared__ float pl[192*68];          // [fo][t] padded
  __shared__ int kx[64], ky[64];
  if (threadIdx.x < 64){
    kx[threadIdx.x] = seq[(sb*64 + threadIdx.x)*2 + 0];
    ky[threadIdx.x] = seq[(sb*64 + threadIdx.x)*2 + 1];
  }
  int tq = threadIdx.x >> 4;            // 0..15 -> t = tq*4+tt
  int eq = threadIdx.x & 15;            // e = e0 + eq*2 + ee
  int wid = threadIdx.x >> 6, lane = threadIdx.x & 63;
  float acc[4][2];
  #pragma unroll
  for (int a = 0; a < 4; a++){ acc[a][0] = 0.f; acc[a][1] = 0.f; }

  for (int pass = 0; pass < 16; pass++){
    int f0 = pass*192;
    __syncthreads();
    for (int tt = 0; tt < 16; tt++){
      int t = tt*4 + wid;
      int x0 = kx[t], y0 = ky[t];
      #pragma unroll
      for (int fo3 = 0; fo3 < 3; fo3++){
        int fo = fo3*64 + lane;
        int f = f0 + fo;
        int cch = f >> 10, rem = f & 1023, ii = rem >> 5, jj = rem & 31;
        int yy = y0 + ii - PADW, xx = x0 + jj - PADW;
        float v = 0.f;
        if ((unsigned)yy < 512u && (unsigned)xx < 512u)
          v = img[((size_t)cch*512 + yy)*512 + xx];
        pl[fo*68 + t] = v;
      }
    }
    __syncthreads();
    for (int fo = 0; fo < 192; fo++){
      float4 pv = *(float4*)&pl[fo*68 + tq*4];
      float2 wv = *(const float2*)&wpet[(size_t)(f0+fo)*256 + e0 + eq*2];
      acc[0][0] += pv.x*wv.x; acc[0][1] += pv.x*wv.y;
      acc[1][0] += pv.y*wv.x; acc[1][1] += pv.y*wv.y;
      acc[2][0] += pv.z*wv.x; acc[2][1] += pv.z*wv.y;
      acc[3][0] += pv.w*wv.x; acc[3][1] += pv.w*wv.y;
    }
  }
  float2 bp = *(const float2*)&b_pe[e0 + eq*2];
  #pragma unroll
  for (int tt = 0; tt < 4; tt++){
    int t = tq*4 + tt;
    float2 o; o.x = acc[tt][0] + bp.x; o.y = acc[tt][1] + bp.y;
    *(float2*)&emb[((size_t)b*64 + t)*256 + e0 + eq*2] = o;
  }
}

// ============ enc.mean(axis=1) ============
__global__ void k_encmean(const float* __restrict__ enc, const int* __restrict__ ws_sort,
                          float* __restrict__ encm){
  int b = blockIdx.x >> 3, dc = blockIdx.x & 7;
  int d = dc*256 + threadIdx.x;
  const float* ep = enc + ((size_t)ws_sort[b]*Pn)*ENCD + d;
  float s = 0.f;
  #pragma unroll 4
  for (int p = 0; p < Pn; p++) s += ep[(size_t)p*ENCD];
  encm[b*ENCD + d] = s * (1.f/196.f);
}

// ============ h,c init: [encmean|emb0] @ W_init_{h,c}.T + b ============
// grid 32 = 2 mats * 16 j-chunks(32 j); thread: 4 b * 1 j, K=2304 in 9 chunks of 256
__global__ __launch_bounds__(256) void k_init(const float* __restrict__ encm, const float* __restrict__ emb,
    const float* __restrict__ Wh, const float* __restrict__ bh,
    const float* __restrict__ Wc, const float* __restrict__ bc,
    float* __restrict__ h, float* __restrict__ c){
  int mat = blockIdx.x >> 4, jb = blockIdx.x & 15;
  const float* W   = mat ? Wc : Wh;
  const float* bias= mat ? bc : bh;
  float* outp      = mat ? c : h;
  int j0 = jb*32;
  __shared__ float XT[256*36];
  int bq = threadIdx.x & 7, jq = threadIdx.x >> 3;   // jq<32
  float acc[4] = {0.f,0.f,0.f,0.f};
  for (int ch = 0; ch < 9; ch++){
    int k0 = ch*256;
    __syncthreads();
    {
      int m = threadIdx.x >> 3, kq8 = threadIdx.x & 7;
      #pragma unroll
      for (int i = 0; i < 8; i++){
        int kq = kq8 + i*8;
        int k = k0 + kq*4;
        float4 v;
        if (k < 2048) v = *(const float4*)&encm[m*ENCD + k];
        else          v = *(const float4*)&emb[((size_t)m*64)*256 + (k - 2048)];
        XT[(4*kq+0)*36+m]=v.x; XT[(4*kq+1)*36+m]=v.y; XT[(4*kq+2)*36+m]=v.z; XT[(4*kq+3)*36+m]=v.w;
      }
    }
    __syncthreads();
    int j = j0 + jq;
    const float* wr = W + (size_t)j*XDIM + k0;
    #pragma unroll 2
    for (int k4 = 0; k4 < 64; k4++){
      float4 wv = *(const float4*)(wr + k4*4);
      float4 x0 = *(float4*)&XT[(k4*4+0)*36 + bq*4];
      float4 x1 = *(float4*)&XT[(k4*4+1)*36 + bq*4];
      float4 x2 = *(float4*)&XT[(k4*4+2)*36 + bq*4];
      float4 x3 = *(float4*)&XT[(k4*4+3)*36 + bq*4];
      acc[0] += x0.x*wv.x + x1.x*wv.y + x2.x*wv.z + x3.x*wv.w;
      acc[1] += x0.y*wv.x + x1.y*wv.y + x2.y*wv.z + x3.y*wv.w;
      acc[2] += x0.z*wv.x + x1.z*wv.y + x2.z*wv.z + x3.z*wv.w;
      acc[3] += x0.w*wv.x + x1.w*wv.y + x2.w*wv.z + x3.w*wv.w;
    }
  }
  #pragma unroll
  for (int bb = 0; bb < 4; bb++)
    outp[(bq*4+bb)*DECD + j0 + jq] = acc[bb] + bias[j0 + jq];
}

// ============ att1 = enc_sorted @ W_enc_att.T + b : (6272,2048)@(2048,512) ============
// grid 784 = 196 m-blocks(32) * 4 n-blocks(128); thread 4m*4n
__global__ __launch_bounds__(256) void k_att1(const float* __restrict__ enc, const int* __restrict__ ws_sort,
    const float* __restrict__ Wea, const float* __restrict__ bea, float* __restrict__ att1){
  int nb = blockIdx.x & 3, mb = blockIdx.x >> 2;
  int m0 = mb*32, n0 = nb*128;
  __shared__ float XT[256*36];
  __shared__ unsigned long long rowbase[32];
  if (threadIdx.x < 32){
    int m = m0 + threadIdx.x;
    int bb = m / 196, p = m - bb*196;
    rowbase[threadIdx.x] = ((unsigned long long)ws_sort[bb]*Pn + p)*(unsigned long long)ENCD;
  }
  int mq = threadIdx.x & 7, nq = threadIdx.x >> 3;
  float acc[4][4];
  #pragma unroll
  for (int a=0;a<4;a++){ acc[a][0]=0.f; acc[a][1]=0.f; acc[a][2]=0.f; acc[a][3]=0.f; }
  for (int ch = 0; ch < 8; ch++){
    int k0 = ch*256;
    __syncthreads();
    {
      int m = threadIdx.x >> 3, kq8 = threadIdx.x & 7;
      const float* src = enc + rowbase[m] + k0;
      #pragma unroll
      for (int i = 0; i < 8; i++){
        int kq = kq8 + i*8;
        float4 v = *(const float4*)(src + kq*4);
        XT[(4*kq+0)*36+m]=v.x; XT[(4*kq+1)*36+m]=v.y; XT[(4*kq+2)*36+m]=v.z; XT[(4*kq+3)*36+m]=v.w;
      }
    }
    __syncthreads();
    #pragma unroll 2
    for (int k4 = 0; k4 < 64; k4++){
      float4 x0 = *(float4*)&XT[(k4*4+0)*36 + mq*4];
      float4 x1 = *(float4*)&XT[(k4*4+1)*36 + mq*4];
      float4 x2 = *(float4*)&XT[(k4*4+2)*36 + mq*4];
      float4 x3 = *(float4*)&XT[(k4*4+3)*36 + mq*4];
      #pragma unroll
      for (int nn = 0; nn < 4; nn++){
        const float* wr = Wea + (size_t)(n0 + nq*4 + nn)*ENCD + k0 + k4*4;
        float4 wv = *(const float4*)wr;
        acc[0][nn] += x0.x*wv.x + x1.x*wv.y + x2.x*wv.z + x3.x*wv.w;
        acc[1][nn] += x0.y*wv.x + x1.y*wv.y + x2.y*wv.z + x3.y*wv.w;
        acc[2][nn] += x0.z*wv.x + x1.z*wv.y + x2.z*wv.z + x3.z*wv.w;
        acc[3][nn] += x0.w*wv.x + x1.w*wv.y + x2.w*wv.z + x3.w*wv.w;
      }
    }
  }
  #pragma unroll
  for (int mm = 0; mm < 4; mm++){
    #pragma unroll
    for (int nn = 0; nn < 4; nn++){
      int n = n0 + nq*4 + nn;
      att1[(size_t)(m0 + mq*4 + mm)*ATTD + n] = acc[mm][nn] + bea[n];
    }
  }
}

// ============ step A: [att2|gateRaw|hhRaw](4608 rows) = h @ W.T, K=512, k-split 2 ============
__global__ __launch_bounds__(256) void k_A(const float* __restrict__ h,
    const float* __restrict__ Wdec, const float* __restrict__ Wfb, const float* __restrict__ Whh,
    float* __restrict__ pA){
  int kc = blockIdx.x & 1, jb = blockIdx.x >> 1;   // jb < 36
  int j0 = jb*128, k0 = kc*256;
  __shared__ float XT[256*36];
  {
    int m = threadIdx.x >> 3, kq8 = threadIdx.x & 7;
    const float* src = h + m*DECD + k0;
    #pragma unroll
    for (int i = 0; i < 8; i++){
      int kq = kq8 + i*8;
      float4 v = *(const float4*)(src + kq*4);
      XT[(4*kq+0)*36+m]=v.x; XT[(4*kq+1)*36+m]=v.y; XT[(4*kq+2)*36+m]=v.z; XT[(4*kq+3)*36+m]=v.w;
    }
  }
  __syncthreads();
  int bq = threadIdx.x & 7, jq = threadIdx.x >> 3;
  const float* wrow[4];
  #pragma unroll
  for (int jj = 0; jj < 4; jj++){
    int j = j0 + jq*4 + jj;
    if (j < 512)       wrow[jj] = Wdec + (size_t)j*DECD + k0;
    else if (j < 2560) wrow[jj] = Wfb  + (size_t)(j-512)*DECD + k0;
    else               wrow[jj] = Whh  + (size_t)(j-2560)*DECD + k0;
  }
  float acc[4][4];
  #pragma unroll
  for (int a=0;a<4;a++){ acc[a][0]=0.f; acc[a][1]=0.f; acc[a][2]=0.f; acc[a][3]=0.f; }
  #pragma unroll 2
  for (int k4 = 0; k4 < 64; k4++){
    float4 x0 = *(float4*)&XT[(k4*4+0)*36 + bq*4];
    float4 x1 = *(float4*)&XT[(k4*4+1)*36 + bq*4];
    float4 x2 = *(float4*)&XT[(k4*4+2)*36 + bq*4];
    float4 x3 = *(float4*)&XT[(k4*4+3)*36 + bq*4];
    #pragma unroll
    for (int jj = 0; jj < 4; jj++){
      float4 wv = *(const float4*)(wrow[jj] + k4*4);
      acc[0][jj] += x0.x*wv.x + x1.x*wv.y + x2.x*wv.z + x3.x*wv.w;
      acc[1][jj] += x0.y*wv.x + x1.y*wv.y + x2.y*wv.z + x3.y*wv.w;
      acc[2][jj] += x0.z*wv.x + x1.z*wv.y + x2.z*wv.z + x3.z*wv.w;
      acc[3][jj] += x0.w*wv.x + x1.w*wv.y + x2.w*wv.z + x3.w*wv.w;
    }
  }
  #pragma unroll
  for (int bb = 0; bb < 4; bb++){
    int b = bq*4 + bb;
    #pragma unroll
    for (int jj = 0; jj < 4; jj++)
      pA[(size_t)(kc*32 + b)*4608 + j0 + jq*4 + jj] = acc[bb][jj];
  }
}

// ============ step B1: scores[b][p] = w_full . relu(att1 + att2) + b_full ============
__global__ __launch_bounds__(256) void k_B1(const float* __restrict__ pA, const float* __restrict__ b_dec,
    const float* __restrict__ wfull, const float* __restrict__ bfull,
    const float* __restrict__ att1, float* __restrict__ scores){
  int b = blockIdx.x;
  __shared__ float a2[512], wf[512];
  for (int a = threadIdx.x; a < 512; a += 256){
    a2[a] = pA[(size_t)b*4608 + a] + pA[(size_t)(32+b)*4608 + a] + b_dec[a];
    wf[a] = wfull[a];
  }
  __syncthreads();
  int p = threadIdx.x;
  if (p < Pn){
    const float4* arow = (const float4*)(att1 + ((size_t)b*Pn + p)*ATTD);
    float acc = bfull[0];
    #pragma unroll 4
    for (int a4 = 0; a4 < 128; a4++){
      float4 av = arow[a4];
      float4 tv = *(float4*)&a2[a4*4];
      float4 wv = *(float4*)&wf[a4*4];
      acc += fmaxf(av.x+tv.x,0.f)*wv.x;
      acc += fmaxf(av.y+tv.y,0.f)*wv.y;
      acc += fmaxf(av.z+tv.z,0.f)*wv.z;
      acc += fmaxf(av.w+tv.w,0.f)*wv.w;
    }
    scores[b*256 + p] = acc;
  }
}

// ============ step B2: softmax(redundant) + awe + xa, alphas out ============
// grid 288 = 32 b * 9 (8 d-chunks of 256 + 1 emb/alpha block)
__global__ __launch_bounds__(256) void k_B2(const float* __restrict__ enc, const int* __restrict__ ws_sort,
    const int* __restrict__ ws_len, const float* __restrict__ scores, const float* __restrict__ pA,
    const float* __restrict__ b_fb, const float* __restrict__ emb,
    float* __restrict__ xa, float* __restrict__ out, int t){
  int b = blockIdx.x / 9, dc = blockIdx.x % 9;
  __shared__ float ev[256];
  __shared__ float red[4];
  __shared__ float bc2[2];
  int tid = threadIdx.x;
  int wid = tid >> 6, lane = tid & 63;
  float s = (tid < Pn) ? scores[b*256 + tid] : -1e30f;
  float m = s;
  #pragma unroll
  for (int o = 32; o; o >>= 1) m = fmaxf(m, __shfl_down(m, o));
  if (lane == 0) red[wid] = m;
  __syncthreads();
  if (tid == 0) bc2[0] = fmaxf(fmaxf(red[0],red[1]), fmaxf(red[2],red[3]));
  __syncthreads();
  float smax = bc2[0];
  float e = (tid < Pn) ? expf(s - smax) : 0.f;
  ev[tid] = e;
  float sm = e;
  #pragma unroll
  for (int o = 32; o; o >>= 1) sm += __shfl_down(sm, o);
  if (lane == 0) red[wid] = sm;
  __syncthreads();
  if (tid == 0) bc2[1] = red[0]+red[1]+red[2]+red[3];
  __syncthreads();
  float ssum = bc2[1];

  if (dc < 8){
    int d = dc*256 + tid;
    const float* ep = enc + ((size_t)ws_sort[b]*Pn)*ENCD + d;
    float acc = 0.f;
    #pragma unroll 4
    for (int p = 0; p < Pn; p++) acc += ev[p] * ep[(size_t)p*ENCD];
    float awe = acc / ssum;
    float gp = pA[(size_t)b*4608 + 512 + d] + pA[(size_t)(32+b)*4608 + 512 + d] + b_fb[d];
    float gate = 1.f/(1.f + expf(-gp));
    xa[b*XDIM + d] = gate * awe;
  } else {
    xa[b*XDIM + 2048 + tid] = emb[((size_t)b*64 + t)*256 + tid];
    bool mask = t < ws_len[b];
    if (tid < Pn) out[O_ALPHA + ((size_t)b*64 + t)*Pn + tid] = mask ? (ev[tid]/ssum) : 0.f;
  }
}

// ============ step C: gates partials = xa @ W_ih.T, K=2304, k-split 8 ============
__global__ __launch_bounds__(256) void k_C(const float* __restrict__ xa, const float* __restrict__ Wih,
                                           float* __restrict__ pC){
  int kc = blockIdx.x & 7, jb = blockIdx.x >> 3;   // jb < 16
  int j0 = jb*128, k0 = kc*288;
  __shared__ float XT[288*36];
  {
    int m = threadIdx.x >> 3, kq8 = threadIdx.x & 7;
    const float* src = xa + m*XDIM + k0;
    #pragma unroll
    for (int i = 0; i < 9; i++){
      int kq = kq8 + i*8;
      float4 v = *(const float4*)(src + kq*4);
      XT[(4*kq+0)*36+m]=v.x; XT[(4*kq+1)*36+m]=v.y; XT[(4*kq+2)*36+m]=v.z; XT[(4*kq+3)*36+m]=v.w;
    }
  }
  __syncthreads();
  int bq = threadIdx.x & 7, jq = threadIdx.x >> 3;
  const float* w0 = Wih + (size_t)(j0 + jq*4)*XDIM + k0;
  float acc[4][4];
  #pragma unroll
  for (int a=0;a<4;a++){ acc[a][0]=0.f; acc[a][1]=0.f; acc[a][2]=0.f; acc[a][3]=0.f; }
  #pragma unroll 2
  for (int k4 = 0; k4 < 72; k4++){
    float4 x0 = *(float4*)&XT[(k4*4+0)*36 + bq*4];
    float4 x1 = *(float4*)&XT[(k4*4+1)*36 + bq*4];
    float4 x2 = *(float4*)&XT[(k4*4+2)*36 + bq*4];
    float4 x3 = *(float4*)&XT[(k4*4+3)*36 + bq*4];
    #pragma unroll
    for (int jj = 0; jj < 4; jj++){
      float4 wv = *(const float4*)(w0 + (size_t)jj*XDIM + k4*4);
      acc[0][jj] += x0.x*wv.x + x1.x*wv.y + x2.x*wv.z + x3.x*wv.w;
      acc[1][jj] += x0.y*wv.x + x1.y*wv.y + x2.y*wv.z + x3.y*wv.w;
      acc[2][jj] += x0.z*wv.x + x1.z*wv.y + x2.z*wv.z + x3.z*wv.w;
      acc[3][jj] += x0.w*wv.x + x1.w*wv.y + x2.w*wv.z + x3.w*wv.w;
    }
  }
  #pragma unroll
  for (int bb = 0; bb < 4; bb++){
    int b = bq*4 + bb;
    #pragma unroll
    for (int jj = 0; jj < 4; jj++)
      pC[(size_t)(kc*32 + b)*2048 + j0 + jq*4 + jj] = acc[bb][jj];
  }
}

// ============ step D: reduce partials + LSTM update + preds/stop ============
__global__ __launch_bounds__(256) void k_D(const float* __restrict__ pC, const float* __restrict__ pA,
    const float* __restrict__ b_ih, const float* __restrict__ b_hh,
    float* __restrict__ h, float* __restrict__ c, const int* __restrict__ ws_len,
    const float* __restrict__ W_fc, const float* __restrict__ b_fc,
    const float* __restrict__ W_stop, const float* __restrict__ b_stop,
    float* __restrict__ out, int t){
  int b = blockIdx.x;
  bool mask = t < ws_len[b];
  __shared__ float hn[512];
  for (int j = threadIdx.x; j < 512; j += 256){
    float g[4];
    #pragma unroll
    for (int q = 0; q < 4; q++){
      int jr = q*512 + j;
      float s = b_ih[jr] + b_hh[jr];
      #pragma unroll
      for (int kc = 0; kc < 8; kc++) s += pC[(size_t)(kc*32 + b)*2048 + jr];
      s += pA[(size_t)b*4608 + 2560 + jr] + pA[(size_t)(32+b)*4608 + 2560 + jr];
      g[q] = s;
    }
    float ig = 1.f/(1.f + expf(-g[0]));
    float fg = 1.f/(1.f + expf(-g[1]));
    float gg = tanhf(g[2]);
    float og = 1.f/(1.f + expf(-g[3]));
    float cn = fg*c[b*512 + j] + ig*gg;
    float hv = og*tanhf(cn);
    if (mask){
      c[b*512 + j] = cn;
      h[b*512 + j] = hv;
      hn[j] = hv;
    } else {
      hn[j] = 0.f;
    }
  }
  __syncthreads();
  int w = threadIdx.x >> 6, lane = threadIdx.x & 63;
  if (w < 3){
    const float* wr = (w < 2) ? (W_fc + w*512) : W_stop;
    float a = 0.f;
    #pragma unroll
    for (int i = 0; i < 8; i++){ int k = lane + i*64; a += hn[k]*wr[k]; }
    #pragma unroll
    for (int o = 32; o; o >>= 1) a += __shfl_down(a, o);
    if (lane == 0){
      if (w < 2) out[O_PRED + ((size_t)b*64 + t)*2 + w] = mask ? (a + b_fc[w]) : 0.f;
      else {
        float pv = 1.f/(1.f + expf(-(a + b_stop[0])));
        out[O_STOP + (size_t)b*64 + t] = mask ? pv : 0.f;
      }
    }
  }
}

// ================= host launcher =================
extern "C" void kernel_launch(void* const* d_in, const int* in_sizes, int n_in,
                              void* d_out, int out_size, void* d_ws, size_t ws_size,
                              hipStream_t stream){
  (void)in_sizes; (void)n_in; (void)out_size; (void)ws_size;
  const float* enc_out   = (const float*)d_in[0];
  const float* imgs      = (const float*)d_in[1];
  const int*   seq       = (const int*)d_in[2];
  const float* seqoff    = (const float*)d_in[3];
  const int*   caplen    = (const int*)d_in[4];
  const float* W_pe      = (const float*)d_in[5];
  const float* b_pe      = (const float*)d_in[6];
  const float* W_enc_att = (const float*)d_in[7];
  const float* b_enc_att = (const float*)d_in[8];
  const float* W_dec_att = (const float*)d_in[9];
  const float* b_dec_att = (const float*)d_in[10];
  const float* w_full    = (const float*)d_in[11];
  const float* b_full    = (const float*)d_in[12];
  const float* W_init_h  = (const float*)d_in[13];
  const float* b_init_h  = (const float*)d_in[14];
  const float* W_init_c  = (const float*)d_in[15];
  const float* b_init_c  = (const float*)d_in[16];
  const float* W_fb      = (const float*)d_in[17];
  const float* b_fb      = (const float*)d_in[18];
  const float* W_ih      = (const float*)d_in[19];
  const float* b_ih      = (const float*)d_in[20];
  const float* W_hh      = (const float*)d_in[21];
  const float* b_hh      = (const float*)d_in[22];
  const float* W_fc      = (const float*)d_in[23];
  const float* b_fc      = (const float*)d_in[24];
  const float* W_stop    = (const float*)d_in[25];
  const float* b_stop    = (const float*)d_in[26];

  float* out = (float*)d_out;
  float* ws  = (float*)d_ws;
  int*   wsi = (int*)d_ws;

  k_prep<<<1, 64, 0, stream>>>(caplen, wsi + WS_SORT, wsi + WS_LEN, out);
  k_seqoff<<<16, 256, 0, stream>>>(seqoff, wsi + WS_SORT, out);
  k_wpet<<<3072, 256, 0, stream>>>(W_pe, ws + WS_WPET);
  k_embed<<<256, 256, 0, stream>>>(imgs, seq, wsi + WS_SORT, ws + WS_WPET, b_pe, ws + WS_EMB);
  k_encmean<<<256, 256, 0, stream>>>(enc_out, wsi + WS_SORT, ws + WS_ENCM);
  k_init<<<32, 256, 0, stream>>>(ws + WS_ENCM, ws + WS_EMB, W_init_h, b_init_h, W_init_c, b_init_c,
                                 ws + WS_H, ws + WS_C);
  k_att1<<<784, 256, 0, stream>>>(enc_out, wsi + WS_SORT, W_enc_att, b_enc_att, ws + WS_ATT1);

  for (int t = 0; t < Tn; t++){
    k_A<<<72, 256, 0, stream>>>(ws + WS_H, W_dec_att, W_fb, W_hh, ws + WS_PA);
    k_B1<<<32, 256, 0, stream>>>(ws + WS_PA, b_dec_att, w_full, b_full, ws + WS_ATT1, ws + WS_SCORES);
    k_B2<<<288, 256, 0, stream>>>(enc_out, wsi + WS_SORT, wsi + WS_LEN, ws + WS_SCORES, ws + WS_PA,
                                  b_fb, ws + WS_EMB, ws + WS_XA, out, t);
    k_C<<<128, 256, 0, stream>>>(ws + WS_XA, W_ih, ws + WS_PC);
    k_D<<<32, 256, 0, stream>>>(ws + WS_PC, ws + WS_PA, b_ih, b_hh, ws + WS_H, ws + WS_C,
                                wsi + WS_LEN, W_fc, b_fc, W_stop, b_stop, out, t);
  }
}

// Round 2
// 4058.804 us; speedup vs baseline: 1.3794x; 1.3794x over previous
//
#include <hip/hip_runtime.h>

// ---------------- problem constants ----------------
#define Bn 32
#define Tn 64
#define Pn 196
#define ENCD 2048
#define DECD 512
#define ATTD 512
#define FLATD 3072
#define EMBD 256
#define IMGD 512
#define PADW 24
#define XDIM 2304

typedef unsigned short u16;
typedef __attribute__((ext_vector_type(8))) short bf16x8;
typedef __attribute__((ext_vector_type(4))) float f32x4;

static __device__ __forceinline__ u16 f2bf(float f){
  unsigned int u = __float_as_uint(f);
  unsigned int r = u + 0x7FFFu + ((u >> 16) & 1u);
  return (u16)(r >> 16);
}
static __device__ __forceinline__ float bf2f(u16 u){
  return __uint_as_float(((unsigned int)u) << 16);
}

// ---------------- output offsets (floats) ----------------
#define O_PRED   0
#define O_STOP   4096
#define O_SEQOFF 6144
#define O_LEN    10240
#define O_ALPHA  10272
#define O_SORT   411680

// ---------------- ws offsets: float region ----------------
#define WS_SORT   0         // int[32]
#define WS_LEN    32        // int[32]
#define WS_C      64        // [32][512]
#define WS_SCORES 16448     // [32][256]
#define WS_PA     24640     // [32][4608]  (att2 | gateRaw | hhRaw)
#define WS_GATES  172096    // [32][2048]
#define WS_EMB    237632    // [32][64][256]
#define WS_WPET   761920    // [3072][256]
// float region ends at 1548352 floats = 6,193,408 bytes
// ---------------- ws offsets: ushort (bf16) region ----------------
#define US_H    3096704                  // [32][512]
#define US_XA   (US_H + 16384)           // [32][2304]
#define US_ATT1 (US_XA + 73728)          // [6272][512]
#define US_ENC  (US_ATT1 + 3211264)      // [6272][2048] sorted
#define US_WA   (US_ENC + 12845056)      // [4608][512]
#define US_WIH  (US_WA + 2359296)        // [2048][2304]
#define US_WEA  (US_WIH + 4718592)       // [512][2048]

// ============ prep: stable descending sort ============
__global__ void k_prep(const int* __restrict__ caplen, int* __restrict__ ws_sort,
                       int* __restrict__ ws_len, float* __restrict__ out){
  __shared__ int len[32];
  int i = threadIdx.x;
  if (i < 32) len[i] = caplen[i];
  __syncthreads();
  if (i < 32){
    int li = len[i], r = 0;
    for (int j = 0; j < 32; j++){
      int lj = len[j];
      r += (lj > li) || (lj == li && j < i);
    }
    ws_sort[r] = i;
    ws_len[r]  = li;
    out[O_LEN + r]  = (float)li;
    out[O_SORT + r] = (float)i;
  }
}

__global__ void k_seqoff(const float* __restrict__ seqoff, const int* __restrict__ ws_sort,
                         float* __restrict__ out){
  int idx = blockIdx.x*256 + threadIdx.x;
  int b = idx >> 7, r = idx & 127;
  out[O_SEQOFF + idx] = seqoff[ws_sort[b]*128 + r];
}

__global__ void k_wpet(const float* __restrict__ W_pe, float* __restrict__ wpet){
  int idx = blockIdx.x*256 + threadIdx.x;
  int e = idx / 3072, f = idx - e*3072;
  wpet[f*256 + e] = W_pe[idx];
}

// ============ fp32 -> bf16 weight convert ============
__global__ void k_cvt(const float* __restrict__ src, u16* __restrict__ dst, int n){
  int i = (blockIdx.x*256 + threadIdx.x)*4;
  if (i >= n) return;
  float4 v = *(const float4*)(src + i);
  dst[i+0] = f2bf(v.x); dst[i+1] = f2bf(v.y); dst[i+2] = f2bf(v.z); dst[i+3] = f2bf(v.w);
}

// ============ enc -> sorted bf16 [6272][2048] ============
__global__ void k_encbf(const float* __restrict__ enc, const int* __restrict__ srt,
                        u16* __restrict__ dst){
  int m = blockIdx.x;              // 0..6271
  int b = m / 196, p = m - b*196;
  const float* src = enc + ((size_t)srt[b]*196 + p)*ENCD;
  u16* d = dst + (size_t)m*ENCD;
  int i = threadIdx.x*8;
  float4 v0 = *(const float4*)(src + i);
  float4 v1 = *(const float4*)(src + i + 4);
  bf16x8 s;
  s[0]=(short)f2bf(v0.x); s[1]=(short)f2bf(v0.y); s[2]=(short)f2bf(v0.z); s[3]=(short)f2bf(v0.w);
  s[4]=(short)f2bf(v1.x); s[5]=(short)f2bf(v1.y); s[6]=(short)f2bf(v1.z); s[7]=(short)f2bf(v1.w);
  *(bf16x8*)(d + i) = s;
}

// ============ patch extraction + embedding GEMM (fp32, one-time) ============
__global__ __launch_bounds__(256) void k_embed(const float* __restrict__ imgs,
    const int* __restrict__ seq, const int* __restrict__ ws_sort,
    const float* __restrict__ wpet, const float* __restrict__ b_pe, float* __restrict__ emb){
  int b = blockIdx.x >> 3, ec = blockIdx.x & 7;
  int e0 = ec * 32;
  int sb = ws_sort[b];
  const float* img = imgs + (size_t)sb*(3*512*512);
  __shared__ float pl[192*68];
  __shared__ int kx[64], ky[64];
  if (threadIdx.x < 64){
    kx[threadIdx.x] = seq[(sb*64 + threadIdx.x)*2 + 0];
    ky[threadIdx.x] = seq[(sb*64 + threadIdx.x)*2 + 1];
  }
  int tq = threadIdx.x >> 4;
  int eq = threadIdx.x & 15;
  int wid = threadIdx.x >> 6, lane = threadIdx.x & 63;
  float acc[4][2];
  #pragma unroll
  for (int a = 0; a < 4; a++){ acc[a][0] = 0.f; acc[a][1] = 0.f; }

  for (int pass = 0; pass < 16; pass++){
    int f0 = pass*192;
    __syncthreads();
    for (int tt = 0; tt < 16; tt++){
      int t = tt*4 + wid;
      int x0 = kx[t], y0 = ky[t];
      #pragma unroll
      for (int fo3 = 0; fo3 < 3; fo3++){
        int fo = fo3*64 + lane;
        int f = f0 + fo;
        int cch = f >> 10, rem = f & 1023, ii = rem >> 5, jj = rem & 31;
        int yy = y0 + ii - PADW, xx = x0 + jj - PADW;
        float v = 0.f;
        if ((unsigned)yy < 512u && (unsigned)xx < 512u)
          v = img[((size_t)cch*512 + yy)*512 + xx];
        pl[fo*68 + t] = v;
      }
    }
    __syncthreads();
    for (int fo = 0; fo < 192; fo++){
      float4 pv = *(float4*)&pl[fo*68 + tq*4];
      float2 wv = *(const float2*)&wpet[(size_t)(f0+fo)*256 + e0 + eq*2];
      acc[0][0] += pv.x*wv.x; acc[0][1] += pv.x*wv.y;
      acc[1][0] += pv.y*wv.x; acc[1][1] += pv.y*wv.y;
      acc[2][0] += pv.z*wv.x; acc[2][1] += pv.z*wv.y;
      acc[3][0] += pv.w*wv.x; acc[3][1] += pv.w*wv.y;
    }
  }
  float2 bp = *(const float2*)&b_pe[e0 + eq*2];
  #pragma unroll
  for (int tt = 0; tt < 4; tt++){
    int t = tq*4 + tt;
    float2 o; o.x = acc[tt][0] + bp.x; o.y = acc[tt][1] + bp.y;
    *(float2*)&emb[((size_t)b*64 + t)*256 + e0 + eq*2] = o;
  }
}

// ============ enc.mean(axis=1) ============
__global__ void k_encmean(const float* __restrict__ enc, const int* __restrict__ ws_sort,
                          float* __restrict__ encm_unused, float* __restrict__ encm){
  int b = blockIdx.x >> 3, dc = blockIdx.x & 7;
  int d = dc*256 + threadIdx.x;
  const float* ep = enc + ((size_t)ws_sort[b]*Pn)*ENCD + d;
  float s = 0.f;
  #pragma unroll 4
  for (int p = 0; p < Pn; p++) s += ep[(size_t)p*ENCD];
  encm[b*ENCD + d] = s * (1.f/196.f);
}

// ============ h,c init (fp32 compute; h stored bf16) ============
__global__ __launch_bounds__(256) void k_init(const float* __restrict__ encm, const float* __restrict__ emb,
    const float* __restrict__ Wh, const float* __restrict__ bh,
    const float* __restrict__ Wc, const float* __restrict__ bc,
    u16* __restrict__ h_bf, float* __restrict__ c){
  int mat = blockIdx.x >> 4, jb = blockIdx.x & 15;
  const float* W    = mat ? Wc : Wh;
  const float* bias = mat ? bc : bh;
  int j0 = jb*32;
  __shared__ float XT[256*36];
  int bq = threadIdx.x & 7, jq = threadIdx.x >> 3;
  float acc[4] = {0.f,0.f,0.f,0.f};
  for (int ch = 0; ch < 9; ch++){
    int k0 = ch*256;
    __syncthreads();
    {
      int m = threadIdx.x >> 3, kq8 = threadIdx.x & 7;
      #pragma unroll
      for (int i = 0; i < 8; i++){
        int kq = kq8 + i*8;
        int k = k0 + kq*4;
        float4 v;
        if (k < 2048) v = *(const float4*)&encm[m*ENCD + k];
        else          v = *(const float4*)&emb[((size_t)m*64)*256 + (k - 2048)];
        XT[(4*kq+0)*36+m]=v.x; XT[(4*kq+1)*36+m]=v.y; XT[(4*kq+2)*36+m]=v.z; XT[(4*kq+3)*36+m]=v.w;
      }
    }
    __syncthreads();
    int j = j0 + jq;
    const float* wr = W + (size_t)j*XDIM + k0;
    #pragma unroll 2
    for (int k4 = 0; k4 < 64; k4++){
      float4 wv = *(const float4*)(wr + k4*4);
      float4 x0 = *(float4*)&XT[(k4*4+0)*36 + bq*4];
      float4 x1 = *(float4*)&XT[(k4*4+1)*36 + bq*4];
      float4 x2 = *(float4*)&XT[(k4*4+2)*36 + bq*4];
      float4 x3 = *(float4*)&XT[(k4*4+3)*36 + bq*4];
      acc[0] += x0.x*wv.x + x1.x*wv.y + x2.x*wv.z + x3.x*wv.w;
      acc[1] += x0.y*wv.x + x1.y*wv.y + x2.y*wv.z + x3.y*wv.w;
      acc[2] += x0.z*wv.x + x1.z*wv.y + x2.z*wv.z + x3.z*wv.w;
      acc[3] += x0.w*wv.x + x1.w*wv.y + x2.w*wv.z + x3.w*wv.w;
    }
  }
  #pragma unroll
  for (int bb = 0; bb < 4; bb++){
    float v = acc[bb] + bias[j0 + jq];
    int row = bq*4 + bb;
    if (mat == 0) h_bf[row*DECD + j0 + jq] = f2bf(v);
    else          c[row*DECD + j0 + jq] = v;
  }
}

// ============ att1 (bf16 MFMA): [6272][2048] @ [2048][512]^T -> bf16 ============
__global__ __launch_bounds__(256) void k_att1(const u16* __restrict__ enc_bf,
    const u16* __restrict__ Wea, const float* __restrict__ bea, u16* __restrict__ att1){
  int mb = blockIdx.x >> 3, jb = blockIdx.x & 7;
  int wv = threadIdx.x >> 6, l = threadIdx.x & 63;
  int lr = l & 15, lh = l >> 4;
  int m0 = mb*64, j0 = jb*64 + wv*16;
  const u16* ap = enc_bf + (size_t)(m0 + lr)*ENCD + lh*8;
  const u16* bp = Wea + (size_t)(j0 + lr)*ENCD + lh*8;
  f32x4 acc0 = {0,0,0,0}, acc1 = {0,0,0,0}, acc2 = {0,0,0,0}, acc3 = {0,0,0,0};
  #pragma unroll 2
  for (int k0 = 0; k0 < ENCD; k0 += 32){
    bf16x8 bv = *(const bf16x8*)(bp + k0);
    bf16x8 a0 = *(const bf16x8*)(ap + k0);
    bf16x8 a1 = *(const bf16x8*)(ap + 16*ENCD + k0);
    bf16x8 a2 = *(const bf16x8*)(ap + 32*ENCD + k0);
    bf16x8 a3 = *(const bf16x8*)(ap + 48*ENCD + k0);
    acc0 = __builtin_amdgcn_mfma_f32_16x16x32_bf16(a0, bv, acc0, 0, 0, 0);
    acc1 = __builtin_amdgcn_mfma_f32_16x16x32_bf16(a1, bv, acc1, 0, 0, 0);
    acc2 = __builtin_amdgcn_mfma_f32_16x16x32_bf16(a2, bv, acc2, 0, 0, 0);
    acc3 = __builtin_amdgcn_mfma_f32_16x16x32_bf16(a3, bv, acc3, 0, 0, 0);
  }
  int j = j0 + lr;
  float bias = bea[j];
  #pragma unroll
  for (int r = 0; r < 4; r++){
    int rr = lh*4 + r;
    att1[(size_t)(m0 +  0 + rr)*ATTD + j] = f2bf(acc0[r] + bias);
    att1[(size_t)(m0 + 16 + rr)*ATTD + j] = f2bf(acc1[r] + bias);
    att1[(size_t)(m0 + 32 + rr)*ATTD + j] = f2bf(acc2[r] + bias);
    att1[(size_t)(m0 + 48 + rr)*ATTD + j] = f2bf(acc3[r] + bias);
  }
}

// ============ step A: pA[32][4608] = h_bf @ W_A^T (MFMA) ============
__global__ __launch_bounds__(256) void k_A(const u16* __restrict__ h_bf,
    const u16* __restrict__ WA, float* __restrict__ pA){
  int wv = threadIdx.x >> 6, l = threadIdx.x & 63;
  int lr = l & 15, lh = l >> 4;
  int j0 = blockIdx.x*64 + wv*16;
  const u16* ha = h_bf + lr*DECD + lh*8;
  const u16* wb = WA + (size_t)(j0 + lr)*DECD + lh*8;
  f32x4 acc0 = {0,0,0,0}, acc1 = {0,0,0,0};
  #pragma unroll 4
  for (int k0 = 0; k0 < DECD; k0 += 32){
    bf16x8 bv = *(const bf16x8*)(wb + k0);
    bf16x8 a0 = *(const bf16x8*)(ha + k0);
    bf16x8 a1 = *(const bf16x8*)(ha + 16*DECD + k0);
    acc0 = __builtin_amdgcn_mfma_f32_16x16x32_bf16(a0, bv, acc0, 0, 0, 0);
    acc1 = __builtin_amdgcn_mfma_f32_16x16x32_bf16(a1, bv, acc1, 0, 0, 0);
  }
  int j = j0 + lr;
  #pragma unroll
  for (int r = 0; r < 4; r++){
    int rr = lh*4 + r;
    pA[(size_t)rr*4608 + j]        = acc0[r];
    pA[(size_t)(16 + rr)*4608 + j] = acc1[r];
  }
}

// ============ step B1: scores ============
__global__ __launch_bounds__(256) void k_B1(const float* __restrict__ pA, const float* __restrict__ b_dec,
    const float* __restrict__ wfull, const float* __restrict__ bfull,
    const u16* __restrict__ att1, const int* __restrict__ ws_len,
    float* __restrict__ scores, int t){
  int b = blockIdx.x >> 2, pc = blockIdx.x & 3;
  if (t >= ws_len[b]) return;
  __shared__ float a2[512], wf[512];
  for (int a = threadIdx.x; a < 512; a += 256){
    a2[a] = pA[(size_t)b*4608 + a] + b_dec[a];
    wf[a] = wfull[a];
  }
  __syncthreads();
  int pl = threadIdx.x >> 2, ac = threadIdx.x & 3;
  int p = pc*49 + pl;
  float acc = 0.f;
  if (pl < 49){
    const u16* row = att1 + ((size_t)(b*196 + p))*ATTD + ac*128;
    const float* a2p = a2 + ac*128;
    const float* wfp = wf + ac*128;
    #pragma unroll 4
    for (int i = 0; i < 16; i++){
      bf16x8 v = *(const bf16x8*)(row + i*8);
      #pragma unroll
      for (int q = 0; q < 8; q++){
        int a = i*8 + q;
        acc += fmaxf(bf2f((u16)v[q]) + a2p[a], 0.f) * wfp[a];
      }
    }
  }
  acc += __shfl_xor(acc, 1);
  acc += __shfl_xor(acc, 2);
  if (pl < 49 && ac == 0) scores[b*256 + p] = acc + bfull[0];
}

// ============ step B2: softmax + awe + gate + xa_bf, alphas ============
__global__ __launch_bounds__(256) void k_B2(const u16* __restrict__ enc_bf,
    const int* __restrict__ ws_len, const float* __restrict__ scores, const float* __restrict__ pA,
    const float* __restrict__ b_fb, const float* __restrict__ emb,
    u16* __restrict__ xa_bf, float* __restrict__ out, int t){
  int b = blockIdx.x / 9, dc = blockIdx.x % 9;
  int tid = threadIdx.x;
  if (t >= ws_len[b]){
    if (dc == 8 && tid < Pn) out[O_ALPHA + ((size_t)b*64 + t)*Pn + tid] = 0.f;
    return;
  }
  __shared__ float ev[256];
  __shared__ float red[4];
  __shared__ float bc2[2];
  int wid = tid >> 6, lane = tid & 63;
  float s = (tid < Pn) ? scores[b*256 + tid] : -1e30f;
  float m = s;
  #pragma unroll
  for (int o = 32; o; o >>= 1) m = fmaxf(m, __shfl_down(m, o));
  if (lane == 0) red[wid] = m;
  __syncthreads();
  if (tid == 0) bc2[0] = fmaxf(fmaxf(red[0],red[1]), fmaxf(red[2],red[3]));
  __syncthreads();
  float smax = bc2[0];
  float e = (tid < Pn) ? expf(s - smax) : 0.f;
  ev[tid] = e;
  float sm = e;
  #pragma unroll
  for (int o = 32; o; o >>= 1) sm += __shfl_down(sm, o);
  if (lane == 0) red[wid] = sm;
  __syncthreads();
  if (tid == 0) bc2[1] = red[0]+red[1]+red[2]+red[3];
  __syncthreads();
  float ssum = bc2[1];

  if (dc < 8){
    int d = dc*256 + tid;
    const u16* ep = enc_bf + (size_t)(b*196)*ENCD + d;
    float acc = 0.f;
    #pragma unroll 4
    for (int p = 0; p < Pn; p++) acc += ev[p] * bf2f(ep[(size_t)p*ENCD]);
    float awe = acc / ssum;
    float gp = pA[(size_t)b*4608 + 512 + d] + b_fb[d];
    float gate = 1.f/(1.f + expf(-gp));
    xa_bf[b*XDIM + d] = f2bf(gate * awe);
  } else {
    xa_bf[b*XDIM + 2048 + tid] = f2bf(emb[((size_t)b*64 + t)*256 + tid]);
    if (tid < Pn) out[O_ALPHA + ((size_t)b*64 + t)*Pn + tid] = ev[tid]/ssum;
  }
}

// ============ step C: gates[32][2048] = xa_bf @ W_ih^T + b_ih + b_hh + hh (MFMA) ============
__global__ __launch_bounds__(64) void k_C(const u16* __restrict__ xa_bf,
    const u16* __restrict__ Wih, const float* __restrict__ pA,
    const float* __restrict__ b_ih, const float* __restrict__ b_hh,
    float* __restrict__ gates){
  int l = threadIdx.x;
  int lr = l & 15, lh = l >> 4;
  int j0 = blockIdx.x*16;
  const u16* xp = xa_bf + lr*XDIM + lh*8;
  const u16* wp = Wih + (size_t)(j0 + lr)*XDIM + lh*8;
  f32x4 acc0 = {0,0,0,0}, acc1 = {0,0,0,0};
  #pragma unroll 4
  for (int k0 = 0; k0 < XDIM; k0 += 32){
    bf16x8 bv = *(const bf16x8*)(wp + k0);
    bf16x8 a0 = *(const bf16x8*)(xp + k0);
    bf16x8 a1 = *(const bf16x8*)(xp + 16*XDIM + k0);
    acc0 = __builtin_amdgcn_mfma_f32_16x16x32_bf16(a0, bv, acc0, 0, 0, 0);
    acc1 = __builtin_amdgcn_mfma_f32_16x16x32_bf16(a1, bv, acc1, 0, 0, 0);
  }
  int j = j0 + lr;
  float bias = b_ih[j] + b_hh[j];
  #pragma unroll
  for (int r = 0; r < 4; r++){
    int b0 = lh*4 + r;
    gates[(size_t)b0*2048 + j]      = acc0[r] + bias + pA[(size_t)b0*4608 + 2560 + j];
    gates[(size_t)(16+b0)*2048 + j] = acc1[r] + bias + pA[(size_t)(16+b0)*4608 + 2560 + j];
  }
}

// ============ step D: LSTM elementwise + preds/stop ============
__global__ __launch_bounds__(256) void k_D(const float* __restrict__ gates,
    float* __restrict__ c, u16* __restrict__ h_bf, const int* __restrict__ ws_len,
    const float* __restrict__ W_fc, const float* __restrict__ b_fc,
    const float* __restrict__ W_stop, const float* __restrict__ b_stop,
    float* __restrict__ out, int t){
  int b = blockIdx.x;
  bool mask = t < ws_len[b];
  __shared__ float hn[512];
  for (int j = threadIdx.x; j < 512; j += 256){
    float gi = gates[(size_t)b*2048 + j];
    float gf = gates[(size_t)b*2048 + 512 + j];
    float gg = gates[(size_t)b*2048 + 1024 + j];
    float go = gates[(size_t)b*2048 + 1536 + j];
    float ig = 1.f/(1.f + expf(-gi));
    float fg = 1.f/(1.f + expf(-gf));
    float gt = tanhf(gg);
    float og = 1.f/(1.f + expf(-go));
    float cn = fg*c[b*512 + j] + ig*gt;
    float hv = og*tanhf(cn);
    if (mask){
      c[b*512 + j] = cn;
      h_bf[b*512 + j] = f2bf(hv);
      hn[j] = hv;
    } else {
      hn[j] = 0.f;
    }
  }
  __syncthreads();
  int w = threadIdx.x >> 6, lane = threadIdx.x & 63;
  if (w < 3){
    const float* wr = (w < 2) ? (W_fc + w*512) : W_stop;
    float a = 0.f;
    #pragma unroll
    for (int i = 0; i < 8; i++){ int k = lane + i*64; a += hn[k]*wr[k]; }
    #pragma unroll
    for (int o = 32; o; o >>= 1) a += __shfl_down(a, o);
    if (lane == 0){
      if (w < 2) out[O_PRED + ((size_t)b*64 + t)*2 + w] = mask ? (a + b_fc[w]) : 0.f;
      else {
        float pv = 1.f/(1.f + expf(-(a + b_stop[0])));
        out[O_STOP + (size_t)b*64 + t] = mask ? pv : 0.f;
      }
    }
  }
}

// ================= host launcher =================
extern "C" void kernel_launch(void* const* d_in, const int* in_sizes, int n_in,
                              void* d_out, int out_size, void* d_ws, size_t ws_size,
                              hipStream_t stream){
  (void)in_sizes; (void)n_in; (void)out_size; (void)ws_size;
  const float* enc_out   = (const float*)d_in[0];
  const float* imgs      = (const float*)d_in[1];
  const int*   seq       = (const int*)d_in[2];
  const float* seqoff    = (const float*)d_in[3];
  const int*   caplen    = (const int*)d_in[4];
  const float* W_pe      = (const float*)d_in[5];
  const float* b_pe      = (const float*)d_in[6];
  const float* W_enc_att = (const float*)d_in[7];
  const float* b_enc_att = (const float*)d_in[8];
  const float* W_dec_att = (const float*)d_in[9];
  const float* b_dec_att = (const float*)d_in[10];
  const float* w_full    = (const float*)d_in[11];
  const float* b_full    = (const float*)d_in[12];
  const float* W_init_h  = (const float*)d_in[13];
  const float* b_init_h  = (const float*)d_in[14];
  const float* W_init_c  = (const float*)d_in[15];
  const float* b_init_c  = (const float*)d_in[16];
  const float* W_fb      = (const float*)d_in[17];
  const float* b_fb      = (const float*)d_in[18];
  const float* W_ih      = (const float*)d_in[19];
  const float* b_ih      = (const float*)d_in[20];
  const float* W_hh      = (const float*)d_in[21];
  const float* b_hh      = (const float*)d_in[22];
  const float* W_fc      = (const float*)d_in[23];
  const float* b_fc      = (const float*)d_in[24];
  const float* W_stop    = (const float*)d_in[25];
  const float* b_stop    = (const float*)d_in[26];

  float* out = (float*)d_out;
  float* ws  = (float*)d_ws;
  int*   wsi = (int*)d_ws;
  u16*   us  = (u16*)d_ws;

  u16* H_BF   = us + US_H;
  u16* XA_BF  = us + US_XA;
  u16* ATT1BF = us + US_ATT1;
  u16* ENC_BF = us + US_ENC;
  u16* WA_BF  = us + US_WA;
  u16* WIH_BF = us + US_WIH;
  u16* WEA_BF = us + US_WEA;

  k_prep<<<1, 64, 0, stream>>>(caplen, wsi + WS_SORT, wsi + WS_LEN, out);
  k_seqoff<<<16, 256, 0, stream>>>(seqoff, wsi + WS_SORT, out);
  k_wpet<<<3072, 256, 0, stream>>>(W_pe, ws + WS_WPET);
  k_embed<<<256, 256, 0, stream>>>(imgs, seq, wsi + WS_SORT, ws + WS_WPET, b_pe, ws + WS_EMB);
  k_encbf<<<6272, 256, 0, stream>>>(enc_out, wsi + WS_SORT, ENC_BF);
  // weight converts: W_A = [W_dec_att | W_fb | W_hh], then W_ea, W_ih
  k_cvt<<<256, 256, 0, stream>>>(W_dec_att, WA_BF, 512*512);
  k_cvt<<<1024, 256, 0, stream>>>(W_fb,  WA_BF + 262144, 2048*512);
  k_cvt<<<1024, 256, 0, stream>>>(W_hh,  WA_BF + 1310720, 2048*512);
  k_cvt<<<1024, 256, 0, stream>>>(W_enc_att, WEA_BF, 512*2048);
  k_cvt<<<4608, 256, 0, stream>>>(W_ih, WIH_BF, 2048*2304);
  k_encmean<<<256, 256, 0, stream>>>(enc_out, wsi + WS_SORT, nullptr, ws + WS_GATES); // reuse GATES as encm scratch
  k_init<<<32, 256, 0, stream>>>(ws + WS_GATES, ws + WS_EMB, W_init_h, b_init_h, W_init_c, b_init_c,
                                 H_BF, ws + WS_C);
  k_att1<<<784, 256, 0, stream>>>(ENC_BF, WEA_BF, b_enc_att, ATT1BF);

  for (int t = 0; t < Tn; t++){
    k_A<<<72, 256, 0, stream>>>(H_BF, WA_BF, ws + WS_PA);
    k_B1<<<128, 256, 0, stream>>>(ws + WS_PA, b_dec_att, w_full, b_full, ATT1BF,
                                  wsi + WS_LEN, ws + WS_SCORES, t);
    k_B2<<<288, 256, 0, stream>>>(ENC_BF, wsi + WS_LEN, ws + WS_SCORES, ws + WS_PA,
                                  b_fb, ws + WS_EMB, XA_BF, out, t);
    k_C<<<128, 64, 0, stream>>>(XA_BF, WIH_BF, ws + WS_PA, b_ih, b_hh, ws + WS_GATES);
    k_D<<<32, 256, 0, stream>>>(ws + WS_GATES, ws + WS_C, H_BF, wsi + WS_LEN,
                                W_fc, b_fc, W_stop, b_stop, out, t);
  }
}